// Round 3
// baseline (191.876 us; speedup 1.0000x reference)
//
#include <hip/hip_runtime.h>
#include <stdint.h>

#define NBATCH 16
#define NOBS   16384     // MAX_DIM
#define NSUP   8192
#define NQRY   4096
#define NTOT   12288
#define DIMV   128       // 512 floats = 128 float4
#define NBINS  2048
#define BINSHIFT 12      // 23-bit key >> 12 -> 11-bit bin

__device__ __forceinline__ uint32_t rotl32(uint32_t x, int r) {
  return (x << r) | (x >> (32 - r));
}

// Exact JAX threefry2x32 with key = (0, 42). Verified vs Random123 KAT.
__device__ __forceinline__ void threefry2x32_k42(uint32_t& x0, uint32_t& x1) {
  const uint32_t ks0 = 0u;
  const uint32_t ks1 = 42u;
  const uint32_t ks2 = 0u ^ 42u ^ 0x1BD11BDAu;
  x0 += ks0; x1 += ks1;
#define TF_ROUND(r) { x0 += x1; x1 = rotl32(x1, (r)); x1 ^= x0; }
  TF_ROUND(13) TF_ROUND(15) TF_ROUND(26) TF_ROUND(6)
  x0 += ks1; x1 += ks2 + 1u;
  TF_ROUND(17) TF_ROUND(29) TF_ROUND(16) TF_ROUND(24)
  x0 += ks2; x1 += ks0 + 2u;
  TF_ROUND(13) TF_ROUND(15) TF_ROUND(26) TF_ROUND(6)
  x0 += ks0; x1 += ks1 + 3u;
  TF_ROUND(17) TF_ROUND(29) TF_ROUND(16) TF_ROUND(24)
  x0 += ks1; x1 += ks2 + 4u;
  TF_ROUND(13) TF_ROUND(15) TF_ROUND(26) TF_ROUND(6)
  x0 += ks2; x1 += ks0 + 5u;
#undef TF_ROUND
}

// Partitionable threefry (jax_threefry_partitionable=True, JAX default):
// per-element 64-bit counter = flat index fed as (hi=0, lo=f); output
// word = x0 ^ x1.   [CONFIRMED bit-exact on Output 0 in round 2]
__device__ __forceinline__ uint32_t jax_random_bits(uint32_t f) {
  uint32_t x0 = 0u, x1 = f;
  threefry2x32_k42(x0, x1);
  return x0 ^ x1;
}

// One block per batch row. Exact ranks of descending-stable sort of the
// JAX uniform scores; perm[b][rank] = source index for rank < NTOT.
__global__ void __launch_bounds__(1024)
fobs_rank_kernel(int* __restrict__ perm) {
  __shared__ uint32_t bkey[NOBS];      // 64 KB
  __shared__ uint16_t bidx[NOBS];      // 32 KB
  __shared__ uint32_t hist[NBINS];     // 8 KB
  __shared__ uint32_t basearr[NBINS];  // 8 KB
  __shared__ uint32_t cursor[NBINS];   // 8 KB

  const int b   = blockIdx.x;
  const int tid = threadIdx.x;

  for (int i = tid; i < NBINS; i += 1024) hist[i] = 0u;
  __syncthreads();

  uint32_t mykey[16];
#pragma unroll
  for (int i = 0; i < 16; ++i) {
    const uint32_t f = (uint32_t)(b * NOBS + i * 1024 + tid);
    const uint32_t key = jax_random_bits(f) >> 9;  // 23-bit mantissa bits;
    mykey[i] = key;                                // monotone-injective in score
    atomicAdd(&hist[key >> BINSHIFT], 1u);
  }
  __syncthreads();

  // basearr[bin] = #elements in higher bins (higher key = earlier rank)
  if (tid == 0) {
    uint32_t acc = 0;
    for (int bin = NBINS - 1; bin >= 0; --bin) { basearr[bin] = acc; acc += hist[bin]; }
  }
  __syncthreads();
  for (int i = tid; i < NBINS; i += 1024) cursor[i] = basearr[i];
  __syncthreads();

#pragma unroll
  for (int i = 0; i < 16; ++i) {
    const uint32_t key = mykey[i];
    const uint32_t pos = atomicAdd(&cursor[key >> BINSHIFT], 1u);
    bkey[pos] = key;
    bidx[pos] = (uint16_t)(i * 1024 + tid);
  }
  __syncthreads();

  // Exact rank: descending key; ties -> ascending index (stable lax.top_k)
#pragma unroll 1
  for (int i = 0; i < 16; ++i) {
    const uint32_t key = mykey[i];
    const uint32_t idx = (uint32_t)(i * 1024 + tid);
    const uint32_t bin = key >> BINSHIFT;
    const uint32_t lob = basearr[bin];
    const uint32_t end = lob + hist[bin];
    uint32_t cnt = 0;
    for (uint32_t q = lob; q < end; ++q) {
      const uint32_t kq = bkey[q];
      const uint32_t iq = (uint32_t)bidx[q];
      if (kq > key || (kq == key && iq < idx)) ++cnt;
    }
    const uint32_t rank = lob + cnt;
    if (rank < NTOT) perm[b * NTOT + rank] = (int)idx;
  }
}

// One wave per output row: copy 512 floats (128 float4).
__global__ void __launch_bounds__(256)
fobs_gather_kernel(const float4* __restrict__ emb,
                   const int* __restrict__ perm,
                   float4* __restrict__ out) {
  const int w    = threadIdx.x >> 6;
  const int lane = threadIdx.x & 63;
  const int row  = blockIdx.x * 4 + w;        // 0 .. NBATCH*NTOT-1
  const int b    = row / NTOT;
  const int r    = row - b * NTOT;
  const int src  = perm[row];
  const float4* s = emb + (size_t)src * DIMV;
  size_t dofs;
  if (r < NSUP) dofs = ((size_t)b * NSUP + r) * DIMV;
  else          dofs = (size_t)NBATCH * NSUP * DIMV
                     + ((size_t)b * NQRY + (size_t)(r - NSUP)) * DIMV;
  float4* d = out + dofs;
  d[lane]      = s[lane];
  d[lane + 64] = s[lane + 64];
}

extern "C" void kernel_launch(void* const* d_in, const int* in_sizes, int n_in,
                              void* d_out, int out_size, void* d_ws, size_t ws_size,
                              hipStream_t stream) {
  const float* emb = (const float*)d_in[0];
  int* perm = (int*)d_ws;  // NBATCH*NTOT ints = 768 KB

  fobs_rank_kernel<<<NBATCH, 1024, 0, stream>>>(perm);
  fobs_gather_kernel<<<(NBATCH * NTOT) / 4, 256, 0, stream>>>(
      (const float4*)emb, perm, (float4*)d_out);
}

// Round 4
// 160.034 us; speedup vs baseline: 1.1990x; 1.1990x over previous
//
#include <hip/hip_runtime.h>
#include <stdint.h>

#define NBATCH 16
#define NOBS   16384     // MAX_DIM
#define NSUP   8192
#define NQRY   4096
#define NTOT   12288
#define DIMV   128       // 512 floats = 128 float4
#define NBINS  4096
#define BINSHIFT 11      // 23-bit key >> 11 -> 12-bit bin (avg 4/bin)

__device__ __forceinline__ uint32_t rotl32(uint32_t x, int r) {
  return (x << r) | (x >> (32 - r));
}

// Exact JAX threefry2x32 with key = (0, 42). Verified vs Random123 KAT.
__device__ __forceinline__ void threefry2x32_k42(uint32_t& x0, uint32_t& x1) {
  const uint32_t ks0 = 0u;
  const uint32_t ks1 = 42u;
  const uint32_t ks2 = 0u ^ 42u ^ 0x1BD11BDAu;
  x0 += ks0; x1 += ks1;
#define TF_ROUND(r) { x0 += x1; x1 = rotl32(x1, (r)); x1 ^= x0; }
  TF_ROUND(13) TF_ROUND(15) TF_ROUND(26) TF_ROUND(6)
  x0 += ks1; x1 += ks2 + 1u;
  TF_ROUND(17) TF_ROUND(29) TF_ROUND(16) TF_ROUND(24)
  x0 += ks2; x1 += ks0 + 2u;
  TF_ROUND(13) TF_ROUND(15) TF_ROUND(26) TF_ROUND(6)
  x0 += ks0; x1 += ks1 + 3u;
  TF_ROUND(17) TF_ROUND(29) TF_ROUND(16) TF_ROUND(24)
  x0 += ks1; x1 += ks2 + 4u;
  TF_ROUND(13) TF_ROUND(15) TF_ROUND(26) TF_ROUND(6)
  x0 += ks2; x1 += ks0 + 5u;
#undef TF_ROUND
}

// Partitionable threefry (jax default): counter = (0, flat_index),
// output word = x0 ^ x1.  [CONFIRMED bit-exact in round 2/3]
__device__ __forceinline__ uint32_t jax_random_bits(uint32_t f) {
  uint32_t x0 = 0u, x1 = f;
  threefry2x32_k42(x0, x1);
  return x0 ^ x1;
}

// One block per batch row. Exact ranks of descending-stable sort of the
// JAX uniform scores; perm[b][rank] = source index for rank < NTOT.
__global__ void __launch_bounds__(1024)
fobs_rank_kernel(int* __restrict__ perm) {
  __shared__ uint32_t bkey[NOBS];      // 64 KB
  __shared__ uint16_t bidx[NOBS];      // 32 KB
  __shared__ uint32_t hist[NBINS];     // 16 KB
  __shared__ uint32_t basearr[NBINS];  // 16 KB  (scan ping buffer)
  __shared__ uint32_t cursor[NBINS];   // 16 KB  (scan pong buffer)
                                       // total 144 KB <= 160 KB

  const int b   = blockIdx.x;
  const int tid = threadIdx.x;
  const int K   = NBINS / 1024;        // 4 bins per thread

  for (int i = tid; i < NBINS; i += 1024) hist[i] = 0u;
  __syncthreads();

  uint32_t mykey[16];
#pragma unroll
  for (int i = 0; i < 16; ++i) {
    const uint32_t f = (uint32_t)(b * NOBS + i * 1024 + tid);
    const uint32_t key = jax_random_bits(f) >> 9;  // 23-bit; monotone in score
    mykey[i] = key;
    atomicAdd(&hist[key >> BINSHIFT], 1u);
  }
  __syncthreads();

  // Parallel inclusive SUFFIX scan of hist (Hillis-Steele, ping-pong).
  // After the loop, src[i] = sum_{j>=i} hist[j].
  {
    uint32_t* src = basearr;
    uint32_t* dst = cursor;
    for (int i = tid; i < NBINS; i += 1024) src[i] = hist[i];
    __syncthreads();
    for (int off = 1; off < NBINS; off <<= 1) {
      for (int i = tid; i < NBINS; i += 1024)
        dst[i] = src[i] + ((i + off < NBINS) ? src[i + off] : 0u);
      __syncthreads();
      uint32_t* t = src; src = dst; dst = t;
    }
    // base[bin] = #elements in higher bins = inclusive_suffix[bin+1]
    uint32_t vals[4];
#pragma unroll
    for (int k = 0; k < K; ++k) {
      const int i = tid + k * 1024;
      vals[k] = (i + 1 < NBINS) ? src[i + 1] : 0u;
    }
    __syncthreads();
#pragma unroll
    for (int k = 0; k < K; ++k) {
      const int i = tid + k * 1024;
      basearr[i] = vals[k];
      cursor[i]  = vals[k];
    }
  }
  __syncthreads();

  // Bucket scatter (order within bucket irrelevant; exact compare later)
#pragma unroll
  for (int i = 0; i < 16; ++i) {
    const uint32_t key = mykey[i];
    const uint32_t pos = atomicAdd(&cursor[key >> BINSHIFT], 1u);
    bkey[pos] = key;
    bidx[pos] = (uint16_t)(i * 1024 + tid);
  }
  __syncthreads();

  // Exact rank: descending key; ties -> ascending index (stable lax.top_k)
#pragma unroll 1
  for (int i = 0; i < 16; ++i) {
    const uint32_t key = mykey[i];
    const uint32_t idx = (uint32_t)(i * 1024 + tid);
    const uint32_t bin = key >> BINSHIFT;
    const uint32_t lob = basearr[bin];
    const uint32_t end = lob + hist[bin];
    uint32_t cnt = 0;
    for (uint32_t q = lob; q < end; ++q) {
      const uint32_t kq = bkey[q];
      const uint32_t iq = (uint32_t)bidx[q];
      if (kq > key || (kq == key && iq < idx)) ++cnt;
    }
    const uint32_t rank = lob + cnt;
    if (rank < NTOT) perm[b * NTOT + rank] = (int)idx;
  }
}

// One wave per output row: copy 512 floats (128 float4).
__global__ void __launch_bounds__(256)
fobs_gather_kernel(const float4* __restrict__ emb,
                   const int* __restrict__ perm,
                   float4* __restrict__ out) {
  const int w    = threadIdx.x >> 6;
  const int lane = threadIdx.x & 63;
  const int row  = blockIdx.x * 4 + w;        // 0 .. NBATCH*NTOT-1
  const int b    = row / NTOT;
  const int r    = row - b * NTOT;
  const int src  = perm[row];
  const float4* s = emb + (size_t)src * DIMV;
  size_t dofs;
  if (r < NSUP) dofs = ((size_t)b * NSUP + r) * DIMV;
  else          dofs = (size_t)NBATCH * NSUP * DIMV
                     + ((size_t)b * NQRY + (size_t)(r - NSUP)) * DIMV;
  float4* d = out + dofs;
  d[lane]      = s[lane];
  d[lane + 64] = s[lane + 64];
}

extern "C" void kernel_launch(void* const* d_in, const int* in_sizes, int n_in,
                              void* d_out, int out_size, void* d_ws, size_t ws_size,
                              hipStream_t stream) {
  const float* emb = (const float*)d_in[0];
  int* perm = (int*)d_ws;  // NBATCH*NTOT ints = 768 KB

  fobs_rank_kernel<<<NBATCH, 1024, 0, stream>>>(perm);
  fobs_gather_kernel<<<(NBATCH * NTOT) / 4, 256, 0, stream>>>(
      (const float4*)emb, perm, (float4*)d_out);
}

// Round 5
// 157.594 us; speedup vs baseline: 1.2175x; 1.0155x over previous
//
#include <hip/hip_runtime.h>
#include <stdint.h>

#define NBATCH 16
#define NOBS   16384     // MAX_DIM (per batch row)
#define NELEM  (NBATCH * NOBS)
#define NSUP   8192
#define NQRY   4096
#define NTOT   12288
#define DIMV   128       // 512 floats = 128 float4
#define NBINS  4096
#define BINSHIFT 11      // 23-bit key >> 11 -> 12-bit bin (avg 4/bin)

typedef float f32x4 __attribute__((ext_vector_type(4)));

__device__ __forceinline__ uint32_t rotl32(uint32_t x, int r) {
  return (x << r) | (x >> (32 - r));
}

// Exact JAX threefry2x32 with key = (0, 42). Verified vs Random123 KAT.
__device__ __forceinline__ void threefry2x32_k42(uint32_t& x0, uint32_t& x1) {
  const uint32_t ks0 = 0u;
  const uint32_t ks1 = 42u;
  const uint32_t ks2 = 0u ^ 42u ^ 0x1BD11BDAu;
  x0 += ks0; x1 += ks1;
#define TF_ROUND(r) { x0 += x1; x1 = rotl32(x1, (r)); x1 ^= x0; }
  TF_ROUND(13) TF_ROUND(15) TF_ROUND(26) TF_ROUND(6)
  x0 += ks1; x1 += ks2 + 1u;
  TF_ROUND(17) TF_ROUND(29) TF_ROUND(16) TF_ROUND(24)
  x0 += ks2; x1 += ks0 + 2u;
  TF_ROUND(13) TF_ROUND(15) TF_ROUND(26) TF_ROUND(6)
  x0 += ks0; x1 += ks1 + 3u;
  TF_ROUND(17) TF_ROUND(29) TF_ROUND(16) TF_ROUND(24)
  x0 += ks1; x1 += ks2 + 4u;
  TF_ROUND(13) TF_ROUND(15) TF_ROUND(26) TF_ROUND(6)
  x0 += ks2; x1 += ks0 + 5u;
#undef TF_ROUND
}

// Partitionable threefry (jax default): counter = (0, flat_index),
// output word = x0 ^ x1.  [CONFIRMED bit-exact rounds 2-4]
// key = bits >> 9: the 23 mantissa bits, monotone-injective in the score.
__device__ __forceinline__ uint32_t jax_key(uint32_t f) {
  uint32_t x0 = 0u, x1 = f;
  threefry2x32_k42(x0, x1);
  return (x0 ^ x1) >> 9;
}

// Packed within-bin comparator value: (key_low11 << 14) | (16383 - idx).
// Within one bin, q beats m (earlier rank) <=> packed_q > packed_m.
__device__ __forceinline__ uint32_t pack_cmp(uint32_t key, uint32_t idx_in_row) {
  return ((key & 0x7FFu) << 14) | (16383u - idx_in_row);
}

// Stage 1: per-batch 4096-bin histogram of keys (hist pre-zeroed via memset).
__global__ void __launch_bounds__(256)
k_hist(uint32_t* __restrict__ hist) {
  const uint32_t g = blockIdx.x * 256 + threadIdx.x;   // 0..NELEM-1
  const uint32_t key = jax_key(g);
  atomicAdd(&hist[(g >> 14) * NBINS + (key >> BINSHIFT)], 1u);
}

// Stage 2: per-batch suffix scan -> base (elements in higher bins), cursor=base.
__global__ void __launch_bounds__(1024)
k_scan(const uint32_t* __restrict__ hist,
       uint32_t* __restrict__ base,
       uint32_t* __restrict__ cursor) {
  __shared__ uint32_t s0[NBINS];
  __shared__ uint32_t s1[NBINS];
  const int b   = blockIdx.x;
  const int tid = threadIdx.x;

  uint32_t* src = s0;
  uint32_t* dst = s1;
  for (int i = tid; i < NBINS; i += 1024) src[i] = hist[b * NBINS + i];
  __syncthreads();
  for (int off = 1; off < NBINS; off <<= 1) {
    for (int i = tid; i < NBINS; i += 1024)
      dst[i] = src[i] + ((i + off < NBINS) ? src[i + off] : 0u);
    __syncthreads();
    uint32_t* t = src; src = dst; dst = t;
  }
  // base[bin] = inclusive_suffix[bin+1]
  for (int i = tid; i < NBINS; i += 1024) {
    const uint32_t v = (i + 1 < NBINS) ? src[i + 1] : 0u;
    base[b * NBINS + i]   = v;
    cursor[b * NBINS + i] = v;
  }
}

// Stage 3: scatter packed comparators into per-batch bucket array.
__global__ void __launch_bounds__(256)
k_scatter(uint32_t* __restrict__ cursor,
          uint32_t* __restrict__ bucket) {
  const uint32_t g   = blockIdx.x * 256 + threadIdx.x;
  const uint32_t b   = g >> 14;
  const uint32_t key = jax_key(g);
  const uint32_t pos = atomicAdd(&cursor[b * NBINS + (key >> BINSHIFT)], 1u);
  bucket[b * NOBS + pos] = pack_cmp(key, g & 16383u);
}

// Stage 4: exact rank = base[bin] + #bucket-mates beating me; write perm.
__global__ void __launch_bounds__(256)
k_rank(const uint32_t* __restrict__ hist,
       const uint32_t* __restrict__ base,
       const uint32_t* __restrict__ bucket,
       int* __restrict__ perm) {
  const uint32_t g   = blockIdx.x * 256 + threadIdx.x;
  const uint32_t b   = g >> 14;
  const uint32_t key = jax_key(g);
  const uint32_t bin = key >> BINSHIFT;
  const uint32_t me  = pack_cmp(key, g & 16383u);
  const uint32_t lob = base[b * NBINS + bin];
  const uint32_t cntb = hist[b * NBINS + bin];
  const uint32_t* bk = bucket + b * NOBS + lob;
  uint32_t cnt = 0;
  for (uint32_t q = 0; q < cntb; ++q) cnt += (bk[q] > me) ? 1u : 0u;
  const uint32_t rank = lob + cnt;
  if (rank < NTOT) perm[b * NTOT + rank] = (int)(g & 16383u);
}

// One wave per output row: copy 512 floats (128 float4), nontemporal stores.
__global__ void __launch_bounds__(256)
fobs_gather_kernel(const f32x4* __restrict__ emb,
                   const int* __restrict__ perm,
                   f32x4* __restrict__ out) {
  const int w    = threadIdx.x >> 6;
  const int lane = threadIdx.x & 63;
  const int row  = blockIdx.x * 4 + w;        // 0 .. NBATCH*NTOT-1
  const int b    = row / NTOT;
  const int r    = row - b * NTOT;
  const int src  = perm[row];
  const f32x4* s = emb + (size_t)src * DIMV;
  size_t dofs;
  if (r < NSUP) dofs = ((size_t)b * NSUP + r) * DIMV;
  else          dofs = (size_t)NBATCH * NSUP * DIMV
                     + ((size_t)b * NQRY + (size_t)(r - NSUP)) * DIMV;
  f32x4* d = out + dofs;
  __builtin_nontemporal_store(s[lane],      &d[lane]);
  __builtin_nontemporal_store(s[lane + 64], &d[lane + 64]);
}

extern "C" void kernel_launch(void* const* d_in, const int* in_sizes, int n_in,
                              void* d_out, int out_size, void* d_ws, size_t ws_size,
                              hipStream_t stream) {
  const float* emb = (const float*)d_in[0];

  // ws layout (u32 units):
  uint32_t* ws     = (uint32_t*)d_ws;
  int*      perm   = (int*)ws;                   // 196608  (768 KB)
  uint32_t* hist   = ws + 196608;                // 65536   (256 KB)
  uint32_t* base   = hist + NBATCH * NBINS;      // 65536   (256 KB)
  uint32_t* cursor = base + NBATCH * NBINS;      // 65536   (256 KB)
  uint32_t* bucket = cursor + NBATCH * NBINS;    // 262144  (1 MB)
                                                 // total ~2.5 MB

  hipMemsetAsync(hist, 0, NBATCH * NBINS * sizeof(uint32_t), stream);
  k_hist   <<<NELEM / 256, 256, 0, stream>>>(hist);
  k_scan   <<<NBATCH, 1024, 0, stream>>>(hist, base, cursor);
  k_scatter<<<NELEM / 256, 256, 0, stream>>>(cursor, bucket);
  k_rank   <<<NELEM / 256, 256, 0, stream>>>(hist, base, bucket, perm);
  fobs_gather_kernel<<<(NBATCH * NTOT) / 4, 256, 0, stream>>>(
      (const f32x4*)emb, perm, (f32x4*)d_out);
}

// Round 6
// 120.021 us; speedup vs baseline: 1.5987x; 1.3130x over previous
//
#include <hip/hip_runtime.h>
#include <stdint.h>

#define NBATCH 16
#define NOBS   16384     // MAX_DIM (per batch row)
#define NELEM  (NBATCH * NOBS)
#define NSUP   8192
#define NQRY   4096
#define NTOT   12288
#define DIMV   128       // 512 floats = 128 float4
#define NBINS  4096
#define BINSHIFT 11      // 23-bit key >> 11 -> 12-bit bin (avg 4/bin)

typedef float f32x4 __attribute__((ext_vector_type(4)));

__device__ __forceinline__ uint32_t rotl32(uint32_t x, int r) {
  return (x << r) | (x >> (32 - r));
}

// Exact JAX threefry2x32 with key = (0, 42). Verified vs Random123 KAT.
__device__ __forceinline__ void threefry2x32_k42(uint32_t& x0, uint32_t& x1) {
  const uint32_t ks0 = 0u;
  const uint32_t ks1 = 42u;
  const uint32_t ks2 = 0u ^ 42u ^ 0x1BD11BDAu;
  x0 += ks0; x1 += ks1;
#define TF_ROUND(r) { x0 += x1; x1 = rotl32(x1, (r)); x1 ^= x0; }
  TF_ROUND(13) TF_ROUND(15) TF_ROUND(26) TF_ROUND(6)
  x0 += ks1; x1 += ks2 + 1u;
  TF_ROUND(17) TF_ROUND(29) TF_ROUND(16) TF_ROUND(24)
  x0 += ks2; x1 += ks0 + 2u;
  TF_ROUND(13) TF_ROUND(15) TF_ROUND(26) TF_ROUND(6)
  x0 += ks0; x1 += ks1 + 3u;
  TF_ROUND(17) TF_ROUND(29) TF_ROUND(16) TF_ROUND(24)
  x0 += ks1; x1 += ks2 + 4u;
  TF_ROUND(13) TF_ROUND(15) TF_ROUND(26) TF_ROUND(6)
  x0 += ks2; x1 += ks0 + 5u;
#undef TF_ROUND
}

// Partitionable threefry (jax default): counter = (0, flat_index),
// output word = x0 ^ x1.  [CONFIRMED bit-exact rounds 2-5]
// key = bits >> 9: the 23 mantissa bits, monotone-injective in the score.
__device__ __forceinline__ uint32_t jax_key(uint32_t f) {
  uint32_t x0 = 0u, x1 = f;
  threefry2x32_k42(x0, x1);
  return (x0 ^ x1) >> 9;
}

// Packed within-bin comparator: (key_low11 << 14) | (16383 - idx).
// Within one bin, q beats m (earlier rank) <=> packed_q > packed_m.
__device__ __forceinline__ uint32_t pack_cmp(uint32_t key, uint32_t idx_in_row) {
  return ((key & 0x7FFu) << 14) | (16383u - idx_in_row);
}

// Stage 1: per-batch 4096-bin histogram of keys (hist pre-zeroed).
__global__ void __launch_bounds__(256)
k_hist(uint32_t* __restrict__ hist) {
  const uint32_t g = blockIdx.x * 256 + threadIdx.x;   // 0..NELEM-1
  const uint32_t key = jax_key(g);
  atomicAdd(&hist[(g >> 14) * NBINS + (key >> BINSHIFT)], 1u);
}

// Stage 2: per-batch suffix scan -> base (elements in higher bins), cursor=base.
__global__ void __launch_bounds__(1024)
k_scan(const uint32_t* __restrict__ hist,
       uint32_t* __restrict__ base,
       uint32_t* __restrict__ cursor) {
  __shared__ uint32_t s0[NBINS];
  __shared__ uint32_t s1[NBINS];
  const int b   = blockIdx.x;
  const int tid = threadIdx.x;

  uint32_t* src = s0;
  uint32_t* dst = s1;
  for (int i = tid; i < NBINS; i += 1024) src[i] = hist[b * NBINS + i];
  __syncthreads();
  for (int off = 1; off < NBINS; off <<= 1) {
    for (int i = tid; i < NBINS; i += 1024)
      dst[i] = src[i] + ((i + off < NBINS) ? src[i + off] : 0u);
    __syncthreads();
    uint32_t* t = src; src = dst; dst = t;
  }
  for (int i = tid; i < NBINS; i += 1024) {
    const uint32_t v = (i + 1 < NBINS) ? src[i + 1] : 0u;
    base[b * NBINS + i]   = v;
    cursor[b * NBINS + i] = v;
  }
}

// Stage 3: scatter packed comparators into per-batch bucket array.
__global__ void __launch_bounds__(256)
k_scatter(uint32_t* __restrict__ cursor,
          uint32_t* __restrict__ bucket) {
  const uint32_t g   = blockIdx.x * 256 + threadIdx.x;
  const uint32_t b   = g >> 14;
  const uint32_t key = jax_key(g);
  const uint32_t pos = atomicAdd(&cursor[b * NBINS + (key >> BINSHIFT)], 1u);
  bucket[b * NOBS + pos] = pack_cmp(key, g & 16383u);
}

// Stage 4 (fused rank+gather, idx-major): one block per embedding row.
// Lanes 0..15 compute the row's rank in each batch (bucket scan); the row
// is loaded ONCE and stored to every batch where rank < NTOT.
// Read traffic: 32 MB sequential (16x less than rank-major gather).
__global__ void __launch_bounds__(256)
k_gather(const uint32_t* __restrict__ hist,
         const uint32_t* __restrict__ base,
         const uint32_t* __restrict__ bucket,
         const f32x4* __restrict__ emb,
         f32x4* __restrict__ out) {
  __shared__ uint32_t srank[NBATCH];
  const uint32_t idx = blockIdx.x;         // 0..NOBS-1
  const int tid  = threadIdx.x;
  const int w    = tid >> 6;
  const int lane = tid & 63;

  // Issue the row load first; its latency hides the rank computation.
  const f32x4* s = emb + (size_t)idx * DIMV;
  const f32x4 v0 = s[lane];
  const f32x4 v1 = s[lane + 64];

  if (tid < NBATCH) {
    const uint32_t b   = (uint32_t)tid;
    const uint32_t g   = b * NOBS + idx;
    const uint32_t key = jax_key(g);
    const uint32_t bin = key >> BINSHIFT;
    const uint32_t me  = pack_cmp(key, idx);
    const uint32_t lob = base[b * NBINS + bin];
    const uint32_t n   = hist[b * NBINS + bin];
    const uint32_t* bk = bucket + b * NOBS + lob;
    uint32_t cnt = 0;
    for (uint32_t q = 0; q < n; ++q) cnt += (bk[q] > me) ? 1u : 0u;
    srank[b] = lob + cnt;
  }
  __syncthreads();

#pragma unroll
  for (int j = 0; j < 4; ++j) {
    const int b = w * 4 + j;
    const uint32_t r = srank[b];
    if (r < NTOT) {
      size_t dofs;
      if (r < NSUP) dofs = ((size_t)b * NSUP + r) * DIMV;
      else          dofs = (size_t)NBATCH * NSUP * DIMV
                         + ((size_t)b * NQRY + (size_t)(r - NSUP)) * DIMV;
      f32x4* d = out + dofs;
      __builtin_nontemporal_store(v0, &d[lane]);
      __builtin_nontemporal_store(v1, &d[lane + 64]);
    }
  }
}

extern "C" void kernel_launch(void* const* d_in, const int* in_sizes, int n_in,
                              void* d_out, int out_size, void* d_ws, size_t ws_size,
                              hipStream_t stream) {
  const float* emb = (const float*)d_in[0];

  // ws layout (u32 units):
  uint32_t* hist   = (uint32_t*)d_ws;            // 65536   (256 KB)
  uint32_t* base   = hist + NBATCH * NBINS;      // 65536   (256 KB)
  uint32_t* cursor = base + NBATCH * NBINS;      // 65536   (256 KB)
  uint32_t* bucket = cursor + NBATCH * NBINS;    // 262144  (1 MB)

  hipMemsetAsync(hist, 0, NBATCH * NBINS * sizeof(uint32_t), stream);
  k_hist   <<<NELEM / 256, 256, 0, stream>>>(hist);
  k_scan   <<<NBATCH, 1024, 0, stream>>>(hist, base, cursor);
  k_scatter<<<NELEM / 256, 256, 0, stream>>>(cursor, bucket);
  k_gather <<<NOBS, 256, 0, stream>>>(hist, base, bucket,
                                      (const f32x4*)emb, (f32x4*)d_out);
}